// Round 5
// baseline (69.735 us; speedup 1.0000x reference)
//
#include <hip/hip_runtime.h>

#define W 126
#define NPIX 15876      // 126*126
#define NB 16
#define NCH 8
#define NCLS 100

#define GR 3            // rows per wave (same residue)
#define CC 10           // classes per chunk
#define NYCH 10         // class chunks
#define NWAVES (NYCH * NB * 7 * 6)   // 6720
#define NBLK_A (NWAVES / 4)          // 1680

// ws layout (floats): acc[0..255], MT[256..256+49*52), partials at 4096..
#define WS_ACC_OFF 0
#define WS_MT_OFF 256
#define WS_PART_OFF 4096

// ---------------------------------------------------------------------------
// Kernel A: binned contraction of logits with (sigma_x, sigma_y, op, rho).
// Wave handles GR=3 rows sharing residue m = y%7, for CC=10 classes.
// Lane l owns pixels 2l,2l+1 (float2, coalesced). ALL 30 loads are issued
// into three register arrays BEFORE any FMA (explicit 30-deep pipeline —
// round-3's VGPR=32 showed the compiler re-fusing load+use into a serial
// latency chain). Accumulation in 8 registers, no atomics in hot path.
// ---------------------------------------------------------------------------
__global__ __launch_bounds__(256) void ga_reduce(
    const float* __restrict__ logits,
    const float* __restrict__ sx, const float* __restrict__ sy,
    const float* __restrict__ op, const float* __restrict__ rho,
    float* __restrict__ part) {
  __shared__ float s_data[4][64][9];   // 9-pad: conflict-free writes
  __shared__ float s_bin[196];
  __shared__ int   s_m[4];
  const int t    = threadIdx.x;
  const int w    = t >> 6;
  const int lane = t & 63;

  for (int i = t; i < 196; i += 256) s_bin[i] = 0.f;

  const int wid = blockIdx.x * 4 + w;      // 0..6719
  const int cy  = wid / 672;               // class chunk 0..9
  int rem = wid - cy * 672;
  const int b   = rem / 42;                // batch 0..15
  rem -= b * 42;
  const int m   = rem / 6;                 // row residue 0..6
  const int yg  = rem - m * 6;             // row group 0..5
  if (lane == 0) s_m[w] = m;

  float a[4][2];
#pragma unroll
  for (int k = 0; k < 4; ++k) { a[k][0] = 0.f; a[k][1] = 0.f; }

  if (lane < 63) {
    const int c0 = cy * CC;
    const float* img = logits + (size_t)b * NCLS * NPIX + (size_t)c0 * NPIX;
    const int y0 = m + 7 * (yg * GR);
    const float2* r0 =
        reinterpret_cast<const float2*>(img + (size_t)y0 * W) + lane;
    const float2* r1 =
        reinterpret_cast<const float2*>(img + (size_t)(y0 + 7) * W) + lane;
    const float2* r2 =
        reinterpret_cast<const float2*>(img + (size_t)(y0 + 14) * W) + lane;

    float2 v0[CC], v1[CC], v2[CC];
#pragma unroll
    for (int cc = 0; cc < CC; ++cc) v0[cc] = r0[(size_t)cc * (NPIX / 2)];
#pragma unroll
    for (int cc = 0; cc < CC; ++cc) v1[cc] = r1[(size_t)cc * (NPIX / 2)];
#pragma unroll
    for (int cc = 0; cc < CC; ++cc) v2[cc] = r2[(size_t)cc * (NPIX / 2)];

#define FMA_ROW(V)                                                   \
    _Pragma("unroll")                                                \
    for (int cc = 0; cc < CC; ++cc) {                                \
      const int c = c0 + cc;                                         \
      const float p0 = sx[c], p1 = sy[c];                            \
      const float p2 = op[c], p3 = rho[c];                           \
      a[0][0] += V[cc].x * p0; a[0][1] += V[cc].y * p0;              \
      a[1][0] += V[cc].x * p1; a[1][1] += V[cc].y * p1;              \
      a[2][0] += V[cc].x * p2; a[2][1] += V[cc].y * p2;              \
      a[3][0] += V[cc].x * p3; a[3][1] += V[cc].y * p3;              \
    }
    FMA_ROW(v0)
    FMA_ROW(v1)
    FMA_ROW(v2)
#undef FMA_ROW
  }

#pragma unroll
  for (int k = 0; k < 4; ++k) {
    s_data[w][lane][k * 2]     = a[k][0];
    s_data[w][lane][k * 2 + 1] = a[k][1];
  }
  __syncthreads();

  if (t < 112) {                       // (wave, param, x-residue) reducers
    const int ww = t / 28;
    const int k  = (t % 28) / 7;
    const int n  = t % 7;
    float s = 0.f;
#pragma unroll
    for (int j = 0; j < 18; ++j) {     // pixels p = n + 7j of the row
      const int p = n + 7 * j;
      s += s_data[ww][p >> 1][k * 2 + (p & 1)];
    }
    atomicAdd(&s_bin[k * 49 + s_m[ww] * 7 + n], s);
  }
  __syncthreads();

  float* my = part + (size_t)blockIdx.x * 196;
  for (int i = t; i < 196; i += 256) my[i] = s_bin[i];
}

// ---------------------------------------------------------------------------
// Kernel A2: sum 1680 partials. 49 blocks x 4 bins, float4 reads.
// ---------------------------------------------------------------------------
__global__ __launch_bounds__(256) void ga_final(const float* __restrict__ part,
                                                float* __restrict__ acc) {
  __shared__ float4 red[256];
  const int h = blockIdx.x;            // 0..48 -> bins 4h..4h+3
  const int t = threadIdx.x;
  float4 s = make_float4(0.f, 0.f, 0.f, 0.f);
  for (int j = t; j < NBLK_A; j += 256) {
    const float4 v =
        *reinterpret_cast<const float4*>(part + (size_t)j * 196 + h * 4);
    s.x += v.x; s.y += v.y; s.z += v.z; s.w += v.w;
  }
  red[t] = s;
  __syncthreads();
#pragma unroll
  for (int off = 128; off; off >>= 1) {
    if (t < off) {
      red[t].x += red[t + off].x; red[t].y += red[t + off].y;
      red[t].z += red[t + off].z; red[t].w += red[t + off].w;
    }
    __syncthreads();
  }
  if (t == 0) *reinterpret_cast<float4*>(acc + h * 4) = red[0];
}

// ---------------------------------------------------------------------------
// Kernel B: per-point gaussian build + bilinear shift + opacity weight.
// Writes MT[q*52 + p] = wop[p] * kt[p][q] (q-major rows, padded to 52,
// pad entries p=49..51 zeroed).
// ---------------------------------------------------------------------------
__global__ __launch_bounds__(64) void gb_build(const float* __restrict__ acc,
                                               float* __restrict__ MT) {
  __shared__ float s_kern[49][49];
  const int p = threadIdx.x;
  for (int i = p; i < 49; i += 64) {
    MT[i * 52 + 49] = 0.f;
    MT[i * 52 + 50] = 0.f;
    MT[i * 52 + 51] = 0.f;
  }
  if (p < 49) {
    const float inv = 1.0f / 5184.0f;   // mean over BL = 16*18*18
    const float wsx = acc[p]        * inv;
    const float wsy = acc[49 + p]   * inv;
    const float wop = acc[98 + p]   * inv;
    const float wrh = acc[147 + p]  * inv;
    const float av = wsx * wsx + 1e-5f;
    const float dv = wsy * wsy + 1e-5f;
    const float bv = wrh * wsx * wsy;
    const float det = av * dv - bv * bv;
    const float norm = 1.0f / (6.283185307179586f * sqrtf(det));
    float tmp[5][5];
    float mx = 0.f;
#pragma unroll
    for (int i = 0; i < 5; ++i) {
      const float gx = -5.0f + 2.5f * (float)i;
#pragma unroll
      for (int j = 0; j < 5; ++j) {
        const float gy = -5.0f + 2.5f * (float)j;
        const float z = -0.5f * (dv*gx*gx - 2.0f*bv*gx*gy + av*gy*gy) / det;
        const float v = expf(z) * norm;
        tmp[i][j] = v;
        mx = fmaxf(mx, v);
      }
    }
    const float rmx = 1.0f / mx;
#pragma unroll
    for (int i = 0; i < 49; ++i) s_kern[p][i] = 0.f;
#pragma unroll
    for (int i = 0; i < 5; ++i)
#pragma unroll
      for (int j = 0; j < 5; ++j)
        s_kern[p][(i + 1) * 7 + (j + 1)] = tmp[i][j] * rmx;

    const int yp = p / 7, xp = p % 7;
    const float tx = (1.0f - (2.0f * (float)xp) / 7.0f) * 3.0f;
    const float ty = (1.0f - (2.0f * (float)yp) / 7.0f) * 3.0f;
    for (int i = 0; i < 7; ++i) {
      const float yq  = (float)i + ty;
      const float y0f = floorf(yq);
      const float fy  = yq - y0f;
      const int   y0  = (int)y0f;
      for (int j = 0; j < 7; ++j) {
        const float xq  = (float)j + tx;
        const float x0f = floorf(xq);
        const float fx  = xq - x0f;
        const int   x0  = (int)x0f;
        float v = 0.f;
        for (int dy = 0; dy < 2; ++dy) {
          const int yi = y0 + dy;
          if (yi < 0 || yi > 6) continue;
          const float wy = dy ? fy : (1.0f - fy);
          for (int dx = 0; dx < 2; ++dx) {
            const int xi = x0 + dx;
            if (xi < 0 || xi > 6) continue;
            const float wx = dx ? fx : (1.0f - fx);
            v += wy * wx * s_kern[p][yi * 7 + xi];
          }
        }
        MT[(i * 7 + j) * 52 + p] = wop * v;
      }
    }
  }
}

// ---------------------------------------------------------------------------
// Kernel C: splat, register-tiled. Block (128 thr) = 3 patch-row strips of
// one plane. Thread = (strip, patch-triple, yy): 21 outputs (3 patches x
// 7 q). Per K-step r: 3 fv + 7 mv float4 LDS reads feed 84 FMAs ->
// 130 b128 per 21 outputs (1.16 cyc/output vs round-2's 4.9).
// ---------------------------------------------------------------------------
__global__ __launch_bounds__(128) void gc_splat(
    const float* __restrict__ feat, const float* __restrict__ MT,
    float* __restrict__ out) {
  __shared__ __align__(16) float s_mt[49 * 52];
  __shared__ __align__(16) float s_fp[3 * 18 * 52];
  const int t = threadIdx.x;
  {
    const float4* s4 = reinterpret_cast<const float4*>(MT);
    float4* d4 = reinterpret_cast<float4*>(s_mt);
    for (int i = t; i < (49 * 52) / 4; i += 128) d4[i] = s4[i];
  }
  // zero fv pads (LDS is 0xAA-poisoned; pad*0 must not make NaN)
  for (int i = t; i < 3 * 18; i += 128) {
    s_fp[i * 52 + 49] = 0.f;
    s_fp[i * 52 + 50] = 0.f;
    s_fp[i * 52 + 51] = 0.f;
  }
  const int plane = blockIdx.x / 6;
  const int sg    = blockIdx.x - plane * 6;   // patch rows 3sg..3sg+2
  const float* src = feat + (size_t)plane * NPIX + (size_t)sg * (21 * W);
  for (int i = t; i < 21 * W; i += 128) {
    const int y  = i / W;                 // 0..20
    const int x  = i - y * W;
    const int s  = y / 7, py = y - s * 7;
    const int pc = x / 7, px = x - pc * 7;
    s_fp[(s * 18 + pc) * 52 + py * 7 + px] = src[i];
  }
  __syncthreads();

  if (t < 126) {
    const int s  = t / 42;
    const int rm = t - s * 42;
    const int g  = rm / 7;                // patches 3g..3g+2
    const int yy = rm - g * 7;
    const float* mrow = s_mt + (yy * 7) * 52;
    const float* frow = s_fp + (s * 18 + 3 * g) * 52;

    float acc[3][7];
#pragma unroll
    for (int j = 0; j < 3; ++j)
#pragma unroll
      for (int xx = 0; xx < 7; ++xx) acc[j][xx] = 0.f;

#pragma unroll
    for (int r = 0; r < 13; ++r) {
      float4 fv[3];
#pragma unroll
      for (int j = 0; j < 3; ++j)
        fv[j] = *reinterpret_cast<const float4*>(frow + j * 52 + 4 * r);
#pragma unroll
      for (int xx = 0; xx < 7; ++xx) {
        const float4 mv =
            *reinterpret_cast<const float4*>(mrow + xx * 52 + 4 * r);
#pragma unroll
        for (int j = 0; j < 3; ++j)
          acc[j][xx] +=
              fv[j].x * mv.x + fv[j].y * mv.y + fv[j].z * mv.z + fv[j].w * mv.w;
      }
    }

    float* dst = out + (size_t)plane * NPIX +
                 (size_t)((3 * sg + s) * 7 + yy) * W + 21 * g;
#pragma unroll
    for (int j = 0; j < 3; ++j)
#pragma unroll
      for (int xx = 0; xx < 7; ++xx)
        dst[j * 7 + xx] = acc[j][xx];
  }
}

extern "C" void kernel_launch(void* const* d_in, const int* in_sizes, int n_in,
                              void* d_out, int out_size, void* d_ws, size_t ws_size,
                              hipStream_t stream) {
  const float* feat   = (const float*)d_in[0];
  const float* logits = (const float*)d_in[1];
  const float* sx     = (const float*)d_in[2];
  const float* sy     = (const float*)d_in[3];
  const float* op     = (const float*)d_in[4];
  const float* rho    = (const float*)d_in[5];
  float* outp = (float*)d_out;
  float* ws   = (float*)d_ws;
  float* acc  = ws + WS_ACC_OFF;      // 196 floats
  float* MT   = ws + WS_MT_OFF;       // 49*52 floats
  float* part = ws + WS_PART_OFF;     // 1680*196 floats (~1.3 MB)

  ga_reduce<<<NBLK_A, 256, 0, stream>>>(logits, sx, sy, op, rho, part);
  ga_final<<<49, 256, 0, stream>>>(part, acc);
  gb_build<<<1, 64, 0, stream>>>(acc, MT);
  gc_splat<<<NB * NCH * 6, 128, 0, stream>>>(feat, MT, outp);
}

// Round 6
// 62.474 us; speedup vs baseline: 1.1162x; 1.1162x over previous
//
#include <hip/hip_runtime.h>

#define W 126
#define NPIX 15876      // 126*126
#define NB 16
#define NCH 8
#define NCLS 100

#define CC 10           // classes per chunk
#define NYCH 10         // class chunks
#define NPAIR 63        // row pairs (y, y+1), y even
#define NWID (NYCH * NB * NPAIR)     // 10080 waves
#define NBLK_A (NWID / 4)            // 2520 blocks

// ws layout (floats): acc[0..255], MT[256..256+49*52), partials at 4096..
#define WS_ACC_OFF 0
#define WS_MT_OFF 256
#define WS_PART_OFF 4096

// ---------------------------------------------------------------------------
// Kernel A: binned contraction of logits with (sigma_x, sigma_y, op, rho).
// Wave = one (class-chunk, batch, row-pair y,y+1 with y even). 252 floats =
// 63 aligned float4s; lane l (<63) loads float4 f=4l..4l+3 for 10 classes
// (16B/lane, 10 independent dwordx4 in flight). Since 126 % 7 == 0:
//   slot col n = f % 7            (lane/element constant)
//   slot row   = (m + (f>=126))%7 (m = y%7, wave-uniform)
// -> accumulation entirely in 16 registers, zero hot-path atomics.
// Block reduce: regs -> LDS (17-pad, conflict-free), 224 reducer threads
// with compile-time index lists, 224 LDS atomics/block, 196-float partial.
// ---------------------------------------------------------------------------
__global__ __launch_bounds__(256) void ga_reduce(
    const float* __restrict__ logits,
    const float* __restrict__ sx, const float* __restrict__ sy,
    const float* __restrict__ op, const float* __restrict__ rho,
    float* __restrict__ part) {
  __shared__ float s_data[4][64][17];   // 17-pad: 17 coprime 32 banks
  __shared__ float s_bin[196];
  __shared__ int   s_m[4];
  const int t    = threadIdx.x;
  const int w    = t >> 6;
  const int lane = t & 63;

  for (int i = t; i < 196; i += 256) s_bin[i] = 0.f;

  const int wid  = blockIdx.x * 4 + w;        // 0..10079
  const int cy   = wid / (NB * NPAIR);        // class chunk 0..9
  int rem = wid - cy * (NB * NPAIR);
  const int b    = rem / NPAIR;               // batch 0..15
  const int pair = rem - b * NPAIR;           // row pair 0..62 (y = 2*pair)
  const int m    = (2 * pair) % 7;
  if (lane == 0) s_m[w] = m;

  float a[4][4];
#pragma unroll
  for (int k = 0; k < 4; ++k)
#pragma unroll
    for (int e = 0; e < 4; ++e) a[k][e] = 0.f;

  if (lane < 63) {
    const int c0 = cy * CC;
    const float4* base = reinterpret_cast<const float4*>(
        logits + ((size_t)b * NCLS + c0) * NPIX + (size_t)pair * 252) + lane;

    float4 v[CC];
#pragma unroll
    for (int cc = 0; cc < CC; ++cc) v[cc] = base[(size_t)cc * (NPIX / 4)];

#pragma unroll
    for (int cc = 0; cc < CC; ++cc) {
      const int c = c0 + cc;                  // wave-uniform -> s_load
      const float4 vv = v[cc];
      const float p0 = sx[c], p1 = sy[c], p2 = op[c], p3 = rho[c];
      a[0][0] += vv.x * p0; a[0][1] += vv.y * p0; a[0][2] += vv.z * p0; a[0][3] += vv.w * p0;
      a[1][0] += vv.x * p1; a[1][1] += vv.y * p1; a[1][2] += vv.z * p1; a[1][3] += vv.w * p1;
      a[2][0] += vv.x * p2; a[2][1] += vv.y * p2; a[2][2] += vv.z * p2; a[2][3] += vv.w * p2;
      a[3][0] += vv.x * p3; a[3][1] += vv.y * p3; a[3][2] += vv.z * p3; a[3][3] += vv.w * p3;
    }
  }

#pragma unroll
  for (int k = 0; k < 4; ++k) {
    s_data[w][lane][k * 4 + 0] = a[k][0];
    s_data[w][lane][k * 4 + 1] = a[k][1];
    s_data[w][lane][k * 4 + 2] = a[k][2];
    s_data[w][lane][k * 4 + 3] = a[k][3];
  }
  __syncthreads();

  if (t < 224) {                 // (wave, param, row-sel, x-residue) reducers
    const int ww  = t / 56;
    const int r56 = t - ww * 56;
    const int k   = r56 / 14;
    const int rr  = r56 - k * 14;
    const int rs  = rr / 7;      // 0: row y, 1: row y+1
    const int n   = rr - rs * 7; // x % 7
    float s = 0.f;
#pragma unroll
    for (int j = 0; j < 18; ++j) {
      const int f = rs * 126 + n + 7 * j;     // compile-time per (rs,n,j)
      s += s_data[ww][f >> 2][k * 4 + (f & 3)];
    }
    const int mrow = (s_m[ww] + rs) % 7;
    atomicAdd(&s_bin[k * 49 + mrow * 7 + n], s);
  }
  __syncthreads();

  float* my = part + (size_t)blockIdx.x * 196;
  for (int i = t; i < 196; i += 256) my[i] = s_bin[i];
}

// ---------------------------------------------------------------------------
// Kernel A2: sum 2520 partials. 49 blocks x 4 bins, float4 reads.
// ---------------------------------------------------------------------------
__global__ __launch_bounds__(256) void ga_final(const float* __restrict__ part,
                                                float* __restrict__ acc) {
  __shared__ float4 red[256];
  const int h = blockIdx.x;            // 0..48 -> bins 4h..4h+3
  const int t = threadIdx.x;
  float4 s = make_float4(0.f, 0.f, 0.f, 0.f);
  for (int j = t; j < NBLK_A; j += 256) {
    const float4 v =
        *reinterpret_cast<const float4*>(part + (size_t)j * 196 + h * 4);
    s.x += v.x; s.y += v.y; s.z += v.z; s.w += v.w;
  }
  red[t] = s;
  __syncthreads();
#pragma unroll
  for (int off = 128; off; off >>= 1) {
    if (t < off) {
      red[t].x += red[t + off].x; red[t].y += red[t + off].y;
      red[t].z += red[t + off].z; red[t].w += red[t + off].w;
    }
    __syncthreads();
  }
  if (t == 0) *reinterpret_cast<float4*>(acc + h * 4) = red[0];
}

// ---------------------------------------------------------------------------
// Kernel B: per-point gaussian build + bilinear shift + opacity weight.
// Writes MT[q*52 + p] = wop[p] * kt[p][q] (q-major rows, padded to 52).
// ---------------------------------------------------------------------------
__global__ __launch_bounds__(64) void gb_build(const float* __restrict__ acc,
                                               float* __restrict__ MT) {
  __shared__ float s_kern[49][49];
  const int p = threadIdx.x;
  for (int i = p; i < 49; i += 64) {
    MT[i * 52 + 49] = 0.f;
    MT[i * 52 + 50] = 0.f;
    MT[i * 52 + 51] = 0.f;
  }
  if (p < 49) {
    const float inv = 1.0f / 5184.0f;   // mean over BL = 16*18*18
    const float wsx = acc[p]        * inv;
    const float wsy = acc[49 + p]   * inv;
    const float wop = acc[98 + p]   * inv;
    const float wrh = acc[147 + p]  * inv;
    const float av = wsx * wsx + 1e-5f;
    const float dv = wsy * wsy + 1e-5f;
    const float bv = wrh * wsx * wsy;
    const float det = av * dv - bv * bv;
    const float norm = 1.0f / (6.283185307179586f * sqrtf(det));
    float tmp[5][5];
    float mx = 0.f;
#pragma unroll
    for (int i = 0; i < 5; ++i) {
      const float gx = -5.0f + 2.5f * (float)i;
#pragma unroll
      for (int j = 0; j < 5; ++j) {
        const float gy = -5.0f + 2.5f * (float)j;
        const float z = -0.5f * (dv*gx*gx - 2.0f*bv*gx*gy + av*gy*gy) / det;
        const float v = expf(z) * norm;
        tmp[i][j] = v;
        mx = fmaxf(mx, v);
      }
    }
    const float rmx = 1.0f / mx;
#pragma unroll
    for (int i = 0; i < 49; ++i) s_kern[p][i] = 0.f;
#pragma unroll
    for (int i = 0; i < 5; ++i)
#pragma unroll
      for (int j = 0; j < 5; ++j)
        s_kern[p][(i + 1) * 7 + (j + 1)] = tmp[i][j] * rmx;

    const int yp = p / 7, xp = p % 7;
    const float tx = (1.0f - (2.0f * (float)xp) / 7.0f) * 3.0f;
    const float ty = (1.0f - (2.0f * (float)yp) / 7.0f) * 3.0f;
    for (int i = 0; i < 7; ++i) {
      const float yq  = (float)i + ty;
      const float y0f = floorf(yq);
      const float fy  = yq - y0f;
      const int   y0  = (int)y0f;
      for (int j = 0; j < 7; ++j) {
        const float xq  = (float)j + tx;
        const float x0f = floorf(xq);
        const float fx  = xq - x0f;
        const int   x0  = (int)x0f;
        float v = 0.f;
        for (int dy = 0; dy < 2; ++dy) {
          const int yi = y0 + dy;
          if (yi < 0 || yi > 6) continue;
          const float wy = dy ? fy : (1.0f - fy);
          for (int dx = 0; dx < 2; ++dx) {
            const int xi = x0 + dx;
            if (xi < 0 || xi > 6) continue;
            const float wx = dx ? fx : (1.0f - fx);
            v += wy * wx * s_kern[p][yi * 7 + xi];
          }
        }
        MT[(i * 7 + j) * 52 + p] = wop * v;
      }
    }
  }
}

// ---------------------------------------------------------------------------
// Kernel C (round-2 version, known-good): one block per (plane, patch-row)
// strip. out[q] = dot49(feat_patch, MT_row[q]); both staged in LDS.
// ---------------------------------------------------------------------------
__global__ __launch_bounds__(256) void gc_splat(
    const float* __restrict__ feat, const float* __restrict__ MT,
    float* __restrict__ out) {
  __shared__ __align__(16) float s_mt[49 * 52];
  __shared__ __align__(16) float s_fp[18 * 52];
  const int t = threadIdx.x;
  for (int i = t; i < 49 * 52; i += 256) s_mt[i] = MT[i];
  const int blk   = blockIdx.x;           // plane*18 + patch_row
  const int plane = blk / 18;
  const int pr    = blk - plane * 18;
  const float* src = feat + (size_t)plane * NPIX + (size_t)pr * 7 * W;
  for (int i = t; i < 882; i += 256) {
    const int py = i / W;
    const int xx = i - py * W;
    const int pc = xx / 7;
    const int px = xx - pc * 7;
    s_fp[pc * 52 + py * 7 + px] = src[i];
  }
  __syncthreads();
  float* dst = out + (size_t)plane * NPIX + (size_t)pr * 7 * W;
  for (int i = t; i < 882; i += 256) {
    const int yy = i / W;
    const int xx = i - yy * W;
    const int pc = xx / 7;
    const int q  = yy * 7 + (xx - pc * 7);
    const float4* mv = reinterpret_cast<const float4*>(s_mt + q * 52);
    const float4* fv = reinterpret_cast<const float4*>(s_fp + pc * 52);
    float s = 0.f;
#pragma unroll
    for (int r = 0; r < 12; ++r) {
      const float4 mm = mv[r];
      const float4 ff = fv[r];
      s += ff.x * mm.x + ff.y * mm.y + ff.z * mm.z + ff.w * mm.w;
    }
    s += s_fp[pc * 52 + 48] * s_mt[q * 52 + 48];
    dst[i] = s;
  }
}

extern "C" void kernel_launch(void* const* d_in, const int* in_sizes, int n_in,
                              void* d_out, int out_size, void* d_ws, size_t ws_size,
                              hipStream_t stream) {
  const float* feat   = (const float*)d_in[0];
  const float* logits = (const float*)d_in[1];
  const float* sx     = (const float*)d_in[2];
  const float* sy     = (const float*)d_in[3];
  const float* op     = (const float*)d_in[4];
  const float* rho    = (const float*)d_in[5];
  float* outp = (float*)d_out;
  float* ws   = (float*)d_ws;
  float* acc  = ws + WS_ACC_OFF;      // 196 floats
  float* MT   = ws + WS_MT_OFF;       // 49*52 floats
  float* part = ws + WS_PART_OFF;     // 2520*196 floats (~1.97 MB)

  ga_reduce<<<NBLK_A, 256, 0, stream>>>(logits, sx, sy, op, rho, part);
  ga_final<<<49, 256, 0, stream>>>(part, acc);
  gb_build<<<1, 64, 0, stream>>>(acc, MT);
  gc_splat<<<NB * NCH * 18, 256, 0, stream>>>(feat, MT, outp);
}